// Round 4
// baseline (307.907 us; speedup 1.0000x reference)
//
#include <hip/hip_runtime.h>

#define NNODES 200000
#define NEDGES 3200000
#define NGRAPH 100
#define NPG    2000
#define D      128
#define DOUT   64
#define CAP1   4096     // max distinct layer-1 nodes (expected ~1600)
#define CAP2   8192     // max edges into fetched nodes (expected ~1600)
#define CAPE   65536    // max edges into S1 nodes (expected ~25600)
#define FBUF   1024     // per-block LDS compaction buffer (expected <=~110/block)
#define NBLK   256
#define NTHR   256

// ---- init kernel: must be separate so barrier cells are zero before mega runs ----
__global__ void prek(int* deg, int* s1idx, unsigned char* need,
                     float* agg1, float* agg2, int* cnt, int* bar) {
    int n = blockIdx.x * blockDim.x + threadIdx.x;   // grid covers 524288
    if (n < NNODES) { deg[n] = 0; s1idx[n] = -1; need[n] = 0; }
    if (n < CAP1 * D) agg1[n] = 0.0f;                // 524288 exactly
    if (n < NGRAPH * D) agg2[n] = 0.0f;
    if (n < 8) cnt[n] = 0;
    if (n < 7 * 128) bar[n] = 0;
}

// ---- software grid barrier: 8 counter lines, 1 atomic per block, device fences ----
__device__ __forceinline__ void gridbar(int* bar, int bi) {
    __syncthreads();
    if (threadIdx.x == 0) {
        __threadfence();                              // release: flush prior writes
        atomicAdd(&bar[bi * 128 + (blockIdx.x & 7) * 16], 1);
        int s;
        do {
            s = 0;
            #pragma unroll
            for (int i = 0; i < 8; i++)
                s += __hip_atomic_load(&bar[bi * 128 + i * 16],
                                       __ATOMIC_RELAXED, __HIP_MEMORY_SCOPE_AGENT);
        } while (s < NBLK);
    }
    __syncthreads();
    __threadfence();                                  // acquire: invalidate stale cache
}

__global__ __launch_bounds__(NTHR) void mega(
        const float* __restrict__ feat, const int* __restrict__ src,
        const int4* __restrict__ dst4, const int* __restrict__ to_fetch,
        const float* __restrict__ w1, const float* __restrict__ b1,
        const float* __restrict__ w2, const float* __restrict__ b2,
        const float* __restrict__ w3, const float* __restrict__ b3,
        float* __restrict__ out,
        int* deg, int* s1idx, unsigned char* need,
        int* s1nodes, int* e2src, int* e2slot, int* e1src, int* e1j,
        float* agg1, float* h1n, float* agg2, int* cnt, int* bar) {

    const int tid = threadIdx.x;
    const int bid = blockIdx.x;
    const int gid = bid * NTHR + tid;
    const int NV = NEDGES / 4;

    __shared__ int tf[NGRAPH];
    __shared__ int lcnt, lbase;
    __shared__ int bufs[FBUF], bufj[FBUF];
    __shared__ float sa[8][D];

    // ================= stage A: edges into fetched nodes, mark S1 sources =========
    for (int i = tid; i < NGRAPH; i += NTHR) tf[i] = to_fetch[i];
    if (tid == 0) lcnt = 0;
    __syncthreads();
    for (int v = gid; v < NV; v += NBLK * NTHR) {
        int4 d4 = dst4[v];
        int ds[4] = {d4.x, d4.y, d4.z, d4.w};
        #pragma unroll
        for (int q = 0; q < 4; ++q) {
            int d = ds[q];
            int slot = d / NPG;
            if (tf[slot] == d - slot * NPG) {
                int s = src[v * 4 + q];
                s1idx[s] = -2;                        // benign race, all write -2
                int p = atomicAdd(&lcnt, 1);
                if (p < FBUF) { bufs[p] = s; bufj[p] = slot; }
            }
        }
    }
    __syncthreads();
    {
        int n = min(lcnt, FBUF);
        if (tid == 0) lbase = atomicAdd(&cnt[0], n);
        __syncthreads();
        for (int k = tid; k < n; k += NTHR) {
            int g = lbase + k;
            if (g < CAP2) { e2src[g] = bufs[k]; e2slot[g] = bufj[k]; }
        }
        __syncthreads();
        if (tid == 0) lcnt = 0;
    }
    gridbar(bar, 0);

    // ================= stage compact: dedup S1 sources, assign dense ids ==========
    {
        int n2 = min(cnt[0], CAP2);
        if (bid == 0 && tid < NGRAPH) need[tf[tid] + tid * NPG] = 1;
        for (int k = gid; k < n2; k += NBLK * NTHR) {
            int s = e2src[k];
            bool win = (atomicCAS(&s1idx[s], -2, -4) == -2);
            unsigned long long mask = __ballot(win ? 1 : 0);
            if (mask) {
                int lane = tid & 63;
                int lead = __ffsll(mask) - 1;
                int nw = __popcll(mask);
                int base = 0;
                if (lane == lead) base = atomicAdd(&cnt[1], nw);
                base = __shfl(base, lead, 64);
                if (win) {
                    int idx = base + __popcll(mask & ((1ull << lane) - 1ull));
                    if (idx < CAP1) { s1idx[s] = idx; s1nodes[idx] = s; need[s] = 1; }
                    else s1idx[s] = -1;
                }
            }
        }
    }
    gridbar(bar, 1);

    // ================= stage B: edges into S1 nodes, mark sources needed ==========
    for (int v = gid; v < NV; v += NBLK * NTHR) {
        int4 d4 = dst4[v];
        int ds[4] = {d4.x, d4.y, d4.z, d4.w};
        #pragma unroll
        for (int q = 0; q < 4; ++q) {
            int j = s1idx[ds[q]];
            if (j >= 0) {
                int s = src[v * 4 + q];
                need[s] = 1;                          // benign race
                int p = atomicAdd(&lcnt, 1);
                if (p < FBUF) { bufs[p] = s; bufj[p] = j; }
            }
        }
    }
    __syncthreads();
    {
        int n = min(lcnt, FBUF);
        if (tid == 0) lbase = atomicAdd(&cnt[2], n);
        __syncthreads();
        for (int k = tid; k < n; k += NTHR) {
            int g = lbase + k;
            if (g < CAPE) { e1src[g] = bufs[k]; e1j[g] = bufj[k]; }
        }
    }
    gridbar(bar, 2);

    // ================= stage C: degrees of needed nodes only ======================
    for (int v = gid; v < NV; v += NBLK * NTHR) {
        int4 d4 = dst4[v];
        int ds[4] = {d4.x, d4.y, d4.z, d4.w};
        #pragma unroll
        for (int q = 0; q < 4; ++q)
            if (need[ds[q]]) atomicAdd(&deg[ds[q]], 1);
    }
    gridbar(bar, 3);

    // ================= stage agg1: agg1[j] += feat[s]*norm[s], 8-deep gather ======
    {
        int ne = min(cnt[2], CAPE);
        int col = tid & 127, sub = tid >> 7;          // 2 edge-lanes per block
        for (int base = bid * 2 + sub; base < ne; base += NBLK * 2 * 8) {
            float v[8]; int jj[8];
            #pragma unroll
            for (int u = 0; u < 8; ++u) {
                int e = base + u * NBLK * 2; jj[u] = -1;
                if (e < ne) {
                    int s = e1src[e];
                    jj[u] = e1j[e];
                    v[u] = feat[(size_t)s * D + col] * rsqrtf(fmaxf((float)deg[s], 1.0f));
                }
            }
            #pragma unroll
            for (int u = 0; u < 8; ++u)
                if (jj[u] >= 0) atomicAdd(&agg1[jj[u] * D + col], v[u]);
        }
    }
    gridbar(bar, 4);

    // ================= stage gemm1: h1n = relu((agg1@w1)*nm+b1)*nm, 8 rows/block ==
    {
        int nj = min(cnt[1], CAP1);
        int col = tid & 127, half = tid >> 7;
        for (int g = bid; g * 8 < nj; g += NBLK) {
            __syncthreads();
            for (int x = tid; x < 8 * D; x += NTHR) {
                int r = x >> 7, c = x & 127, row = g * 8 + r;
                sa[r][c] = (row < nj) ? agg1[row * D + c] : 0.0f;
            }
            __syncthreads();
            int r0 = half * 4;
            float a0 = 0, a1 = 0, a2 = 0, a3 = 0;
            #pragma unroll 4
            for (int k = 0; k < D; k++) {
                float w = w1[k * D + col];
                a0 += sa[r0 + 0][k] * w; a1 += sa[r0 + 1][k] * w;
                a2 += sa[r0 + 2][k] * w; a3 += sa[r0 + 3][k] * w;
            }
            float bb = b1[col];
            float accs[4] = {a0, a1, a2, a3};
            #pragma unroll
            for (int i = 0; i < 4; i++) {
                int row = g * 8 + r0 + i;
                if (row < nj) {
                    float nm = rsqrtf(fmaxf((float)deg[s1nodes[row]], 1.0f));
                    h1n[row * D + col] = fmaxf(accs[i] * nm + bb, 0.0f) * nm;
                }
            }
        }
    }
    gridbar(bar, 5);

    // ================= stage agg2: agg2[slot] += h1n[s1idx[src]] ==================
    {
        int n2 = min(cnt[0], CAP2);
        int col = tid & 127, sub = tid >> 7;
        for (int e = bid * 2 + sub; e < n2; e += NBLK * 2) {
            int j = s1idx[e2src[e]];
            if (j >= 0) atomicAdd(&agg2[e2slot[e] * D + col], h1n[j * D + col]);
        }
    }
    gridbar(bar, 6);

    // ================= stage final: h2 = relu((agg2@w2)*nm+b2); out = h2@w3^T+b3 ==
    if (bid < NGRAPH) {
        int i = bid;
        __shared__ float sv[D], h2[D];
        if (tid < D) sv[tid] = agg2[i * D + tid];
        __syncthreads();
        if (tid < D) {
            float acc = 0.0f;
            #pragma unroll 4
            for (int k = 0; k < D; k++) acc += sv[k] * w2[k * D + tid];
            float nm = rsqrtf(fmaxf((float)deg[tf[i] + i * NPG], 1.0f));
            h2[tid] = fmaxf(acc * nm + b2[tid], 0.0f);
        }
        __syncthreads();
        if (tid < DOUT) {
            float o = 0.0f;
            #pragma unroll 4
            for (int k = 0; k < D; k++) o += h2[k] * w3[tid * D + k];
            out[i * DOUT + tid] = o + b3[tid];
        }
    }
}

extern "C" void kernel_launch(void* const* d_in, const int* in_sizes, int n_in,
                              void* d_out, int out_size, void* d_ws, size_t ws_size,
                              hipStream_t stream) {
    const float* feat     = (const float*)d_in[0];
    const int*   src      = (const int*)  d_in[1];
    const int*   dst      = (const int*)  d_in[2];
    const int*   to_fetch = (const int*)  d_in[3];
    const float* w1       = (const float*)d_in[4];
    const float* b1       = (const float*)d_in[5];
    const float* w2       = (const float*)d_in[6];
    const float* b2       = (const float*)d_in[7];
    const float* w3       = (const float*)d_in[8];
    const float* b3       = (const float*)d_in[9];
    float* out = (float*)d_out;
    const int4* dst4 = (const int4*)dst;

    // workspace layout
    char* p = (char*)d_ws;
    int*   deg     = (int*)p;            p += (size_t)NNODES * 4;
    int*   s1idx   = (int*)p;            p += (size_t)NNODES * 4;
    int*   s1nodes = (int*)p;            p += (size_t)CAP1 * 4;
    int*   e2src   = (int*)p;            p += (size_t)CAP2 * 4;
    int*   e2slot  = (int*)p;            p += (size_t)CAP2 * 4;
    int*   e1src   = (int*)p;            p += (size_t)CAPE * 4;
    int*   e1j     = (int*)p;            p += (size_t)CAPE * 4;
    float* agg1    = (float*)p;          p += (size_t)CAP1 * D * 4;
    float* h1n     = (float*)p;          p += (size_t)CAP1 * D * 4;
    float* agg2    = (float*)p;          p += (size_t)NGRAPH * D * 4;
    int*   cnt     = (int*)p;            p += 64;
    int*   bar     = (int*)p;            p += 7 * 128 * 4;
    unsigned char* need = (unsigned char*)p; p += (size_t)NNODES;

    prek<<<(CAP1 * D + 255) / 256, 256, 0, stream>>>(deg, s1idx, need, agg1, agg2, cnt, bar);
    mega<<<NBLK, NTHR, 0, stream>>>(feat, src, dst4, to_fetch, w1, b1, w2, b2, w3, b3,
                                    out, deg, s1idx, need, s1nodes, e2src, e2slot,
                                    e1src, e1j, agg1, h1n, agg2, cnt, bar);
}